// Round 13
// baseline (323.400 us; speedup 1.0000x reference)
//
#include <hip/hip_runtime.h>
#include <cfloat>

#define NPTS   16384
#define MATOMS 8192
#define CH     16
#define ADIM   6
#define KNN    16
#define GROUPS_PER_BLOCK 8     // 32 lanes per point
#define BIGF   1e10f
#define GRIDG  32
#define NCELLS (GRIDG*GRIDG*GRIDG)
#define SLOTS  32              // per-lane capacity (grid lanes are imbalanced)

// classic-path constants (r12 fallback pipeline)
#define CSLOTS 16
#define CHUNK  256
#define NCHUNK (MATOMS/CHUNK)  // 32
#define VMINC  8
#define NPASS  (VMINC + NCHUNK)

// workspace layout (bytes)
#define OFF_POS4   0u
#define OFF_TBUF   131072u
#define OFF_ABAT   655360u
#define OFF_STARTS 688128u          // 32769 ints = 131076 B
#define OFF_SPOS   819216u          // 16B aligned
#define OFF_SBAT   950288u
#define OFF_SIDX   983056u
#define OFF_HDR    999440u
#define WS_NEED    999488u

__device__ __forceinline__ float leakyf(float x) { return x >= 0.0f ? x : 0.2f * x; }

// ---------------------------------------------------------------------------
// Kernel A: per-atom feature MLP t = L3(L2(L1(atomtypes))) + packed pos4
// ---------------------------------------------------------------------------
__global__ void __launch_bounds__(256) prep_kernel(
    const float* __restrict__ atom_xyz,
    const float* __restrict__ atomtypes,
    const int*   __restrict__ atom_batch,
    const float* __restrict__ Wt1, const float* __restrict__ bt1,
    const float* __restrict__ Wt2, const float* __restrict__ bt2,
    const float* __restrict__ Wt3, const float* __restrict__ bt3,
    float4* __restrict__ pos4,
    float*  __restrict__ tbuf,
    int*    __restrict__ abatch)
{
    __shared__ float w1[CH*ADIM], w2[CH*CH], w3[CH*CH], bb1[CH], bb2[CH], bb3[CH];
    const int tid = threadIdx.x;
    if (tid < CH*ADIM) w1[tid] = Wt1[tid];
    if (tid < CH*CH)   { w2[tid] = Wt2[tid]; w3[tid] = Wt3[tid]; }
    if (tid < CH)      { bb1[tid] = bt1[tid]; bb2[tid] = bt2[tid]; bb3[tid] = bt3[tid]; }
    __syncthreads();
    const int m = blockIdx.x * 256 + tid;
    if (m >= MATOMS) return;

    float x[ADIM];
    #pragma unroll
    for (int j = 0; j < ADIM; ++j) x[j] = atomtypes[m*ADIM + j];

    float h0[CH], h1[CH], h2[CH];
    #pragma unroll
    for (int c = 0; c < CH; ++c) {
        float a = 0.0f;
        #pragma unroll
        for (int j = 0; j < ADIM; ++j) a = fmaf(w1[c*ADIM+j], x[j], a);
        h0[c] = leakyf(a + bb1[c]);
    }
    #pragma unroll
    for (int c = 0; c < CH; ++c) {
        float a = 0.0f;
        #pragma unroll
        for (int j = 0; j < CH; ++j) a = fmaf(w2[c*CH+j], h0[j], a);
        h1[c] = leakyf(a + bb2[c]);
    }
    #pragma unroll
    for (int c = 0; c < CH; ++c) {
        float a = 0.0f;
        #pragma unroll
        for (int j = 0; j < CH; ++j) a = fmaf(w3[c*CH+j], h1[j], a);
        h2[c] = leakyf(a + bb3[c]);
    }
    #pragma unroll
    for (int c = 0; c < CH; ++c) tbuf[m*CH + c] = h2[c];

    const float ax = atom_xyz[m*3+0], ay = atom_xyz[m*3+1], az = atom_xyz[m*3+2];
    // np: sum(a*a, -1) = ((ax^2 + ay^2) + az^2), no FMA contraction
    const float a2 = __fadd_rn(__fadd_rn(__fmul_rn(ax,ax), __fmul_rn(ay,ay)), __fmul_rn(az,az));
    pos4[m] = make_float4(ax, ay, az, a2);
    abatch[m] = atom_batch[m];
}

// ---------------------------------------------------------------------------
// Grid build kernels
// ---------------------------------------------------------------------------
__global__ void __launch_bounds__(256) bbox_kernel(
    const float* __restrict__ atom_xyz, float* __restrict__ hdr)
{
    __shared__ float red[6][256];
    const int t = threadIdx.x;
    float mn0=1e30f,mn1=1e30f,mn2=1e30f,mx0=-1e30f,mx1=-1e30f,mx2=-1e30f;
    for (int m = t; m < MATOMS; m += 256) {
        const float x = atom_xyz[m*3+0], y = atom_xyz[m*3+1], z = atom_xyz[m*3+2];
        mn0 = fminf(mn0,x); mn1 = fminf(mn1,y); mn2 = fminf(mn2,z);
        mx0 = fmaxf(mx0,x); mx1 = fmaxf(mx1,y); mx2 = fmaxf(mx2,z);
    }
    red[0][t]=mn0; red[1][t]=mn1; red[2][t]=mn2;
    red[3][t]=mx0; red[4][t]=mx1; red[5][t]=mx2;
    __syncthreads();
    for (int o = 128; o > 0; o >>= 1) {
        if (t < o) {
            red[0][t]=fminf(red[0][t],red[0][t+o]);
            red[1][t]=fminf(red[1][t],red[1][t+o]);
            red[2][t]=fminf(red[2][t],red[2][t+o]);
            red[3][t]=fmaxf(red[3][t],red[3][t+o]);
            red[4][t]=fmaxf(red[4][t],red[4][t+o]);
            red[5][t]=fmaxf(red[5][t],red[5][t+o]);
        }
        __syncthreads();
    }
    if (t == 0) {
        #pragma unroll
        for (int d = 0; d < 3; ++d) {
            const float lo = red[d][0]   - 1e-3f;
            const float hi = red[3+d][0] + 1e-3f;
            const float span = fmaxf(hi - lo, 1e-5f);
            hdr[d]   = lo;
            hdr[3+d] = span / (float)GRIDG;     // cell size s
            hdr[6+d] = (float)GRIDG / span;     // inv_s
        }
    }
}

__device__ __forceinline__ int cell_of(float x, float lo, float inv) {
    int c = (int)((x - lo) * inv);
    return c < 0 ? 0 : (c > GRIDG-1 ? GRIDG-1 : c);
}

__global__ void __launch_bounds__(256) count_kernel(
    const float* __restrict__ atom_xyz, const float* __restrict__ hdr,
    int* __restrict__ counts)
{
    const int m = blockIdx.x * 256 + threadIdx.x;
    if (m >= MATOMS) return;
    const int cx = cell_of(atom_xyz[m*3+0], hdr[0], hdr[6]);
    const int cy = cell_of(atom_xyz[m*3+1], hdr[1], hdr[7]);
    const int cz = cell_of(atom_xyz[m*3+2], hdr[2], hdr[8]);
    atomicAdd(&counts[(cz*GRIDG + cy)*GRIDG + cx], 1);
}

__global__ void __launch_bounds__(1024) prefix_kernel(int* __restrict__ starts)
{
    __shared__ int part[1024];
    const int t = threadIdx.x;
    int v[32];
    const int base = t*32;
    int s = 0;
    #pragma unroll
    for (int j = 0; j < 32; ++j) { v[j] = starts[base+j]; s += v[j]; }
    part[t] = s;
    __syncthreads();
    for (int off = 1; off < 1024; off <<= 1) {
        const int x = (t >= off) ? part[t-off] : 0;
        __syncthreads();
        part[t] += x;
        __syncthreads();
    }
    int run = (t == 0) ? 0 : part[t-1];
    #pragma unroll
    for (int j = 0; j < 32; ++j) { const int cv = v[j]; starts[base+j] = run; run += cv; }
    if (t == 1023) starts[NCELLS] = run;
}

__global__ void __launch_bounds__(256) scatter_kernel(
    const float* __restrict__ atom_xyz, const int* __restrict__ atom_batch,
    const float* __restrict__ hdr, const int* __restrict__ starts,
    int* __restrict__ cursors,
    float4* __restrict__ spos4, int* __restrict__ sbat,
    unsigned short* __restrict__ sidx)
{
    const int m = blockIdx.x * 256 + threadIdx.x;
    if (m >= MATOMS) return;
    const float ax = atom_xyz[m*3+0], ay = atom_xyz[m*3+1], az = atom_xyz[m*3+2];
    const int cx = cell_of(ax, hdr[0], hdr[6]);
    const int cy = cell_of(ay, hdr[1], hdr[7]);
    const int cz = cell_of(az, hdr[2], hdr[8]);
    const int c = (cz*GRIDG + cy)*GRIDG + cx;
    const int slot = starts[c] + atomicAdd(&cursors[c], 1);
    // a2: identical op sequence to prep_kernel -> bitwise-equal .w
    const float a2 = __fadd_rn(__fadd_rn(__fmul_rn(ax,ax), __fmul_rn(ay,ay)), __fmul_rn(az,az));
    spos4[slot] = make_float4(ax, ay, az, a2);
    sbat[slot]  = atom_batch[m];
    sidx[slot]  = (unsigned short)m;
}

// ---------------------------------------------------------------------------
// Kernel B (grid path): 32 lanes/point, no barriers in the hot path.
//   vmin: per-lane lhs-min over 1/8 strided subset (direct global, lazy batch)
//   tau-select: 16 pop-mins over 32 lane minima (validated validity argument)
//   window filter: scan only cells with boxmin^2 <= pn2+tauf+1 (superset by
//     construction; margins cover all fp error), append slot to per-lane seg
//   overflow/empty -> validated full insert-scan fallback (classic arrays)
//   Phase C: EXACT d2 + EXACT batch + lexicographic (d, original idx) insert
//   Final merge + epilogue: validated, unchanged (original-index based)
// ---------------------------------------------------------------------------
__global__ void __launch_bounds__(256) atom_main_grid(
    const float* __restrict__ xyz,
    const int*   __restrict__ batch,
    const float4* __restrict__ pos4,
    const float* __restrict__ tbuf,
    const int*   __restrict__ abatch,
    const int*   __restrict__ starts,
    const float4* __restrict__ spos4,
    const int*   __restrict__ sbat,
    const unsigned short* __restrict__ sidx,
    const float* __restrict__ hdr,
    const float* __restrict__ Watt,
    const float* __restrict__ We1, const float* __restrict__ be1,
    const float* __restrict__ We2, const float* __restrict__ be2,
    const float* __restrict__ We3, const float* __restrict__ be3,
    float* __restrict__ out)
{
    __shared__ float lw1t[CH*CH], lw2t[CH*CH], lw3t[CH*CH];
    __shared__ float lb1[CH], lb2[CH], lb3[CH], lwatt[KNN];
    __shared__ unsigned short lbuf[GROUPS_PER_BLOCK * SLOTS * 32];
    const int tid = threadIdx.x;
    lw1t[tid] = We1[(tid & 15)*CH + (tid >> 4)];
    lw2t[tid] = We2[(tid & 15)*CH + (tid >> 4)];
    lw3t[tid] = We3[(tid & 15)*CH + (tid >> 4)];
    if (tid < CH) { lb1[tid] = be1[tid]; lb2[tid] = be2[tid]; lb3[tid] = be3[tid]; lwatt[tid] = Watt[tid]; }
    __syncthreads();

    const int c32 = tid & 31;
    const int grp = tid >> 5;
    const int n   = blockIdx.x * GROUPS_PER_BLOCK + grp;

    const float px = xyz[n*3+0], py = xyz[n*3+1], pz = xyz[n*3+2];
    // np: sum(x*x, -1) sequential, no FMA
    const float pn2 = __fadd_rn(__fadd_rn(__fmul_rn(px,px), __fmul_rn(py,py)), __fmul_rn(pz,pz));
    const int pb = batch[n];

    // ---- vmin: per-lane lhs-min over 1/8 strided subset (1024 atoms)
    float vmin = FLT_MAX;
    for (int t4 = 0; t4 < 8; ++t4) {
        float4 A[4];
        #pragma unroll
        for (int u = 0; u < 4; ++u) A[u] = pos4[((t4*4 + u)*32 + c32) * 8];
        #pragma unroll
        for (int u = 0; u < 4; ++u) {
            const float dot = fmaf(pz, A[u].z, fmaf(py, A[u].y, __fmul_rn(px, A[u].x)));
            const float lhs = fmaf(-2.0f, dot, A[u].w);
            if (lhs < vmin) {
                if (abatch[((t4*4 + u)*32 + c32) * 8] == pb) vmin = lhs;
            }
        }
    }

    // ---- tau-select: 16 d-only pop-mins over the group's 32 lane minima.
    float tau = FLT_MAX;
    {
        float v = vmin;
        #pragma unroll
        for (int k = 0; k < KNN; ++k) {
            float d = v;
            d = fminf(d, __shfl_xor(d, 1));
            d = fminf(d, __shfl_xor(d, 2));
            d = fminf(d, __shfl_xor(d, 4));
            d = fminf(d, __shfl_xor(d, 8));
            d = fminf(d, __shfl_xor(d, 16));
            tau = d;
            if (v == d) v = FLT_MAX;    // remove popped (ties together: safe)
        }
    }
    const int skip = !(tau < BIGF);     // group-uniform
    const float tauf = tau + (1e-5f*(fabsf(pn2) + fabsf(tau)) + 1e-2f);

    // ---- window filter over grid cells
    int cnt = 0;
    unsigned short* seg = &lbuf[grp * (SLOTS*32) + c32];
    if (!skip) {
        const float lo0 = hdr[0], lo1 = hdr[1], lo2 = hdr[2];
        const float s0 = hdr[3], s1 = hdr[4], s2 = hdr[5];
        const float is0 = hdr[6], is1 = hdr[7], is2 = hdr[8];
        const float tbox = pn2 + tauf + 1.0f;                  // d2-space bound
        const float radd = sqrtf(fmaxf(pn2 + tauf, 0.0f) + 1.0f); // >= sqrt(tbox)
        int x0 = (int)floorf((px - radd - lo0) * is0) - 1;
        int x1 = (int)floorf((px + radd - lo0) * is0) + 1;
        int y0 = (int)floorf((py - radd - lo1) * is1) - 1;
        int y1 = (int)floorf((py + radd - lo1) * is1) + 1;
        int z0 = (int)floorf((pz - radd - lo2) * is2) - 1;
        int z1 = (int)floorf((pz + radd - lo2) * is2) + 1;
        x0 = max(0, min(GRIDG-1, x0)); x1 = max(0, min(GRIDG-1, x1));
        y0 = max(0, min(GRIDG-1, y0)); y1 = max(0, min(GRIDG-1, y1));
        z0 = max(0, min(GRIDG-1, z0)); z1 = max(0, min(GRIDG-1, z1));
        const int wx = x1-x0+1, wy = y1-y0+1, wz = z1-z0+1;
        const int W = wx*wy*wz;
        for (int q = c32; q < W; q += 32) {
            const int qx = q % wx;
            const int qr = q / wx;
            const int qy = qr % wy;
            const int qz = qr / wy;
            const int cx = x0+qx, cy = y0+qy, cz = z0+qz;
            const float bx0 = lo0 + (float)cx*s0;
            const float by0 = lo1 + (float)cy*s1;
            const float bz0 = lo2 + (float)cz*s2;
            const float dx = fmaxf(fmaxf(bx0 - px, px - (bx0+s0)), 0.0f);
            const float dy = fmaxf(fmaxf(by0 - py, py - (by0+s1)), 0.0f);
            const float dz = fmaxf(fmaxf(bz0 - pz, pz - (bz0+s2)), 0.0f);
            const float bmin = dx*dx + dy*dy + dz*dz;
            if (bmin <= tbox) {
                const int c = (cz*GRIDG + cy)*GRIDG + cx;
                const int sb = starts[c], se = starts[c+1];
                for (int sl = sb; sl < se; ++sl) {
                    const float4 a = spos4[sl];
                    const float dot = fmaf(pz, a.z, fmaf(py, a.y, __fmul_rn(px, a.x)));
                    const float lhs = fmaf(-2.0f, dot, a.w);
                    if (lhs <= tauf) {
                        if (cnt < SLOTS) seg[cnt*32] = (unsigned short)sl;
                        ++cnt;
                    }
                }
            }
        }
    }

    // ---- overflow guard: group-or over 32 lanes.
    int ovf = skip | (cnt > SLOTS);
    ovf |= __shfl_xor(ovf, 1);
    ovf |= __shfl_xor(ovf, 2);
    ovf |= __shfl_xor(ovf, 4);
    ovf |= __shfl_xor(ovf, 8);
    ovf |= __shfl_xor(ovf, 16);

    float bd[KNN]; int bi[KNN];
    #pragma unroll
    for (int j = 0; j < KNN; ++j) { bd[j] = FLT_MAX; bi[j] = 0x7fffffff; }

    if (ovf) {
        // validated full insert-scan fallback (classic arrays, original order)
        for (int t = 0; t < MATOMS/32; ++t) {
            const int i = t*32 + c32;
            const float4 a = pos4[i];
            const int ab = abatch[i];
            const float dot = fmaf(pz, a.z, fmaf(py, a.y, __fmul_rn(px, a.x)));
            float d2 = __fsub_rn(__fadd_rn(pn2, a.w), 2.0f * dot);
            d2 = (ab == pb) ? d2 : BIGF;
            if (d2 < bd[KNN-1]) {
                float d = d2; int id = i;
                #pragma unroll
                for (int j = 0; j < KNN; ++j) {
                    const bool sw = d < bd[j];
                    const float od = bd[j]; const int oi = bi[j];
                    bd[j] = sw ? d  : bd[j];
                    bi[j] = sw ? id : bi[j];
                    d  = sw ? od : d;
                    id = sw ? oi : id;
                }
            }
        }
    } else {
        // ---- Phase C: exact top-16 of collected. EXACT d2, EXACT batch,
        // lexicographic (d, original idx) insert -> order-independent.
        for (int s = 0; s < cnt; ++s) {
            const int sl = (int)seg[s*32];
            const float4 a = spos4[sl];
            const float dot = fmaf(pz, a.z, fmaf(py, a.y, __fmul_rn(px, a.x)));
            const float d2 = __fsub_rn(__fadd_rn(pn2, a.w), 2.0f * dot);
            if (sbat[sl] == pb && d2 <= bd[KNN-1]) {
                float d = d2; int id = (int)sidx[sl];
                #pragma unroll
                for (int j = 0; j < KNN; ++j) {
                    const bool sw = (d < bd[j]) || (d == bd[j] && id < bi[j]);
                    const float od = bd[j]; const int oi = bi[j];
                    bd[j] = sw ? d  : bd[j];
                    bi[j] = sw ? id : bi[j];
                    d  = sw ? od : d;
                    id = sw ? oi : id;
                }
            }
        }
    }

    // ---- final merge: 16x pop-min over 32 lanes, lexicographic (d, idx)
    int idxk[KNN];
    #pragma unroll
    for (int k = 0; k < KNN; ++k) {
        float d = bd[0]; int i = bi[0];
        #pragma unroll
        for (int m = 1; m <= 16; m <<= 1) {
            const float pd = __shfl_xor(d, m);
            const int   pi = __shfl_xor(i, m);
            const bool take = (pd < d) || (pd == d && pi < i);
            d = take ? pd : d;
            i = take ? pi : i;
        }
        idxk[k] = i;
        const bool win = (bd[0] == d) && (bi[0] == i);
        if (win) {
            #pragma unroll
            for (int j = 0; j < KNN-1; ++j) { bd[j] = bd[j+1]; bi[j] = bi[j+1]; }
            bd[KNN-1] = FLT_MAX; bi[KNN-1] = 0x7fffffff;
        }
    }

    // ---- Epilogue on lower 16 lanes (validated numerics, unchanged)
    if ((tid & 16) == 0) {
        const int c = tid & 15;
        float ac0 = 0.0f, ac1 = 0.0f, ac2 = 0.0f;
        #pragma unroll
        for (int k = 0; k < KNN; ++k) {
            const int j = idxk[k];
            const float4 a = pos4[j];
            const float v0 = __fsub_rn(px, a.x);
            const float v1 = __fsub_rn(py, a.y);
            const float v2 = __fsub_rn(pz, a.z);
            const float dist = __fadd_rn(__fadd_rn(__fmul_rn(v0,v0), __fmul_rn(v1,v1)), __fmul_rn(v2,v2));
            const float w = 1.0f / __fadd_rn(dist, 1e-8f);   // power(x, -1.0)
            const float nv0 = __fmul_rn(v0, w);
            const float nv1 = __fmul_rn(v1, w);
            const float nv2 = __fmul_rn(v2, w);
            const float fc = tbuf[(size_t)j * CH + c];
            const float fw = __fmul_rn(fc, lwatt[k]);
            ac0 = fmaf(nv0, fw, ac0);
            ac1 = fmaf(nv1, fw, ac1);
            ac2 = fmaf(nv2, fw, ac2);
        }
        const float s = __fadd_rn(__fadd_rn(__fmul_rn(ac0,ac0), __fmul_rn(ac1,ac1)),
                                  __fmul_rn(ac2,ac2));
        const float fx = sqrtf(s);

        float a1 = 0.0f;
        #pragma unroll
        for (int j = 0; j < CH; ++j) {
            const float fj = __shfl(fx, j, 16);
            a1 = fmaf(lw1t[j*CH + c], fj, a1);
        }
        const float g1 = leakyf(a1 + lb1[c]);

        float a2 = 0.0f;
        #pragma unroll
        for (int j = 0; j < CH; ++j) {
            const float gj = __shfl(g1, j, 16);
            a2 = fmaf(lw2t[j*CH + c], gj, a2);
        }
        const float g2 = leakyf(a2 + lb2[c]);

        float a3 = 0.0f;
        #pragma unroll
        for (int j = 0; j < CH; ++j) {
            const float gj = __shfl(g2, j, 16);
            a3 = fmaf(lw3t[j*CH + c], gj, a3);
        }
        out[(size_t)n*CH + c] = a3 + lb3[c];
    }
}

// ---------------------------------------------------------------------------
// Classic main kernel (r12, validated @144us) — ws-size fallback path.
// ---------------------------------------------------------------------------
__global__ void __launch_bounds__(256) atom_main_kernel(
    const float* __restrict__ xyz,
    const int*   __restrict__ batch,
    const float4* __restrict__ pos4,
    const float* __restrict__ tbuf,
    const int*   __restrict__ abatch,
    const float* __restrict__ Watt,
    const float* __restrict__ We1, const float* __restrict__ be1,
    const float* __restrict__ We2, const float* __restrict__ be2,
    const float* __restrict__ We3, const float* __restrict__ be3,
    float* __restrict__ out)
{
    __shared__ float lw1t[CH*CH], lw2t[CH*CH], lw3t[CH*CH];
    __shared__ float lb1[CH], lb2[CH], lb3[CH], lwatt[KNN];
    __shared__ unsigned short lbuf[GROUPS_PER_BLOCK * CSLOTS * 32];
    __shared__ float4 lpos[2][CHUNK];
    const int tid = threadIdx.x;
    lw1t[tid] = We1[(tid & 15)*CH + (tid >> 4)];
    lw2t[tid] = We2[(tid & 15)*CH + (tid >> 4)];
    lw3t[tid] = We3[(tid & 15)*CH + (tid >> 4)];
    if (tid < CH) { lb1[tid] = be1[tid]; lb2[tid] = be2[tid]; lb3[tid] = be3[tid]; lwatt[tid] = Watt[tid]; }

    const int c32 = tid & 31;
    const int grp = tid >> 5;
    const int n   = blockIdx.x * GROUPS_PER_BLOCK + grp;

    const float px = xyz[n*3+0], py = xyz[n*3+1], pz = xyz[n*3+2];
    const float pn2 = __fadd_rn(__fadd_rn(__fmul_rn(px,px), __fmul_rn(py,py)), __fmul_rn(pz,pz));
    const int pb = batch[n];

    if (tid < CHUNK) lpos[0][tid] = pos4[tid];

    float vmin = FLT_MAX;
    float tauf = 0.0f;
    int   skip = 0;
    int   cnt  = 0;
    unsigned short* seg = &lbuf[grp * (CSLOTS*32) + c32];

    for (int g = 0; g < NPASS; ++g) {
        const int cur = g & 1;
        __syncthreads();
        float4 q0;
        const bool pf = (g+1 < NPASS) && (tid < CHUNK);
        if (pf) {
            const int nc = (g+1 < VMINC) ? (g+1) : (g+1-VMINC);
            q0 = pos4[nc*CHUNK + tid];
        }
        if (g == VMINC) {
            float tau = FLT_MAX;
            float v = vmin;
            #pragma unroll
            for (int k = 0; k < KNN; ++k) {
                float d = v;
                d = fminf(d, __shfl_xor(d, 1));
                d = fminf(d, __shfl_xor(d, 2));
                d = fminf(d, __shfl_xor(d, 4));
                d = fminf(d, __shfl_xor(d, 8));
                d = fminf(d, __shfl_xor(d, 16));
                tau = d;
                if (v == d) v = FLT_MAX;
            }
            skip = !(tau < BIGF);
            tauf = tau + (1e-5f*(fabsf(pn2) + fabsf(tau)) + 1e-2f);
        }
        if (g < VMINC) {
            #pragma unroll 4
            for (int t = 0; t < CHUNK/32; ++t) {
                const int il = t*32 + c32;
                const float4 a = lpos[cur][il];
                const float dot = fmaf(pz, a.z, fmaf(py, a.y, __fmul_rn(px, a.x)));
                const float lhs = fmaf(-2.0f, dot, a.w);
                if (lhs < vmin) {
                    if (abatch[g*CHUNK + il] == pb) vmin = lhs;
                }
            }
        } else if (!skip) {
            const int cb = g - VMINC;
            #pragma unroll 4
            for (int t = 0; t < CHUNK/32; ++t) {
                const int il = t*32 + c32;
                const float4 a = lpos[cur][il];
                const float dot = fmaf(pz, a.z, fmaf(py, a.y, __fmul_rn(px, a.x)));
                const float lhs = fmaf(-2.0f, dot, a.w);
                if (lhs <= tauf) {
                    const int gi = cb*CHUNK + il;
                    if (cnt < CSLOTS) seg[cnt*32] = (unsigned short)gi;
                    ++cnt;
                }
            }
        }
        if (pf) lpos[cur^1][tid] = q0;
    }

    int ovf = skip | (cnt > CSLOTS);
    ovf |= __shfl_xor(ovf, 1);
    ovf |= __shfl_xor(ovf, 2);
    ovf |= __shfl_xor(ovf, 4);
    ovf |= __shfl_xor(ovf, 8);
    ovf |= __shfl_xor(ovf, 16);

    float bd[KNN]; int bi[KNN];
    #pragma unroll
    for (int j = 0; j < KNN; ++j) { bd[j] = FLT_MAX; bi[j] = 0x7fffffff; }

    if (ovf) {
        for (int t = 0; t < MATOMS/32; ++t) {
            const int i = t*32 + c32;
            const float4 a = pos4[i];
            const int ab = abatch[i];
            const float dot = fmaf(pz, a.z, fmaf(py, a.y, __fmul_rn(px, a.x)));
            float d2 = __fsub_rn(__fadd_rn(pn2, a.w), 2.0f * dot);
            d2 = (ab == pb) ? d2 : BIGF;
            if (d2 < bd[KNN-1]) {
                float d = d2; int id = i;
                #pragma unroll
                for (int j = 0; j < KNN; ++j) {
                    const bool sw = d < bd[j];
                    const float od = bd[j]; const int oi = bi[j];
                    bd[j] = sw ? d  : bd[j];
                    bi[j] = sw ? id : bi[j];
                    d  = sw ? od : d;
                    id = sw ? oi : id;
                }
            }
        }
    } else {
        for (int s = 0; s < cnt; ++s) {
            const int i = (int)seg[s*32];
            const float4 a = pos4[i];
            const float dot = fmaf(pz, a.z, fmaf(py, a.y, __fmul_rn(px, a.x)));
            const float d2 = __fsub_rn(__fadd_rn(pn2, a.w), 2.0f * dot);
            if (abatch[i] == pb && d2 <= bd[KNN-1]) {
                float d = d2; int id = i;
                #pragma unroll
                for (int j = 0; j < KNN; ++j) {
                    const bool sw = (d < bd[j]) || (d == bd[j] && id < bi[j]);
                    const float od = bd[j]; const int oi = bi[j];
                    bd[j] = sw ? d  : bd[j];
                    bi[j] = sw ? id : bi[j];
                    d  = sw ? od : d;
                    id = sw ? oi : id;
                }
            }
        }
    }

    int idxk[KNN];
    #pragma unroll
    for (int k = 0; k < KNN; ++k) {
        float d = bd[0]; int i = bi[0];
        #pragma unroll
        for (int m = 1; m <= 16; m <<= 1) {
            const float pd = __shfl_xor(d, m);
            const int   pi = __shfl_xor(i, m);
            const bool take = (pd < d) || (pd == d && pi < i);
            d = take ? pd : d;
            i = take ? pi : i;
        }
        idxk[k] = i;
        const bool win = (bd[0] == d) && (bi[0] == i);
        if (win) {
            #pragma unroll
            for (int j = 0; j < KNN-1; ++j) { bd[j] = bd[j+1]; bi[j] = bi[j+1]; }
            bd[KNN-1] = FLT_MAX; bi[KNN-1] = 0x7fffffff;
        }
    }

    if ((tid & 16) == 0) {
        const int c = tid & 15;
        float ac0 = 0.0f, ac1 = 0.0f, ac2 = 0.0f;
        #pragma unroll
        for (int k = 0; k < KNN; ++k) {
            const int j = idxk[k];
            const float4 a = pos4[j];
            const float v0 = __fsub_rn(px, a.x);
            const float v1 = __fsub_rn(py, a.y);
            const float v2 = __fsub_rn(pz, a.z);
            const float dist = __fadd_rn(__fadd_rn(__fmul_rn(v0,v0), __fmul_rn(v1,v1)), __fmul_rn(v2,v2));
            const float w = 1.0f / __fadd_rn(dist, 1e-8f);
            const float nv0 = __fmul_rn(v0, w);
            const float nv1 = __fmul_rn(v1, w);
            const float nv2 = __fmul_rn(v2, w);
            const float fc = tbuf[(size_t)j * CH + c];
            const float fw = __fmul_rn(fc, lwatt[k]);
            ac0 = fmaf(nv0, fw, ac0);
            ac1 = fmaf(nv1, fw, ac1);
            ac2 = fmaf(nv2, fw, ac2);
        }
        const float s = __fadd_rn(__fadd_rn(__fmul_rn(ac0,ac0), __fmul_rn(ac1,ac1)),
                                  __fmul_rn(ac2,ac2));
        const float fx = sqrtf(s);

        float a1 = 0.0f;
        #pragma unroll
        for (int j = 0; j < CH; ++j) {
            const float fj = __shfl(fx, j, 16);
            a1 = fmaf(lw1t[j*CH + c], fj, a1);
        }
        const float g1 = leakyf(a1 + lb1[c]);

        float a2 = 0.0f;
        #pragma unroll
        for (int j = 0; j < CH; ++j) {
            const float gj = __shfl(g1, j, 16);
            a2 = fmaf(lw2t[j*CH + c], gj, a2);
        }
        const float g2 = leakyf(a2 + lb2[c]);

        float a3 = 0.0f;
        #pragma unroll
        for (int j = 0; j < CH; ++j) {
            const float gj = __shfl(g2, j, 16);
            a3 = fmaf(lw3t[j*CH + c], gj, a3);
        }
        out[(size_t)n*CH + c] = a3 + lb3[c];
    }
}

// ---------------------------------------------------------------------------
extern "C" void kernel_launch(void* const* d_in, const int* in_sizes, int n_in,
                              void* d_out, int out_size, void* d_ws, size_t ws_size,
                              hipStream_t stream)
{
    (void)in_sizes; (void)n_in; (void)out_size;
    const float* xyz        = (const float*)d_in[0];
    const float* atom_xyz   = (const float*)d_in[1];
    const float* atomtypes  = (const float*)d_in[2];
    const int*   batch      = (const int*)d_in[3];
    const int*   atom_batch = (const int*)d_in[4];
    const float* Wt1 = (const float*)d_in[5];
    const float* bt1 = (const float*)d_in[6];
    const float* Wt2 = (const float*)d_in[7];
    const float* bt2 = (const float*)d_in[8];
    const float* Wt3 = (const float*)d_in[9];
    const float* bt3 = (const float*)d_in[10];
    const float* Watt = (const float*)d_in[11];
    const float* We1 = (const float*)d_in[12];
    const float* be1 = (const float*)d_in[13];
    const float* We2 = (const float*)d_in[14];
    const float* be2 = (const float*)d_in[15];
    const float* We3 = (const float*)d_in[16];
    const float* be3 = (const float*)d_in[17];

    char* ws = (char*)d_ws;
    float4* pos4  = (float4*)(ws + OFF_POS4);
    float*  tbuf  = (float*)(ws + OFF_TBUF);
    int*    abat  = (int*)(ws + OFF_ABAT);
    float*  out   = (float*)d_out;

    if (ws_size >= WS_NEED) {
        int*    starts  = (int*)(ws + OFF_STARTS);
        float4* spos4   = (float4*)(ws + OFF_SPOS);
        int*    sbat    = (int*)(ws + OFF_SBAT);
        unsigned short* sidx = (unsigned short*)(ws + OFF_SIDX);
        float*  hdr     = (float*)(ws + OFF_HDR);
        int*    cursors = (int*)(ws + OFF_TBUF);   // alias; dead before prep

        hipMemsetAsync(starts, 0, (NCELLS+1)*sizeof(int), stream);
        hipMemsetAsync(cursors, 0, NCELLS*sizeof(int), stream);
        hipLaunchKernelGGL(bbox_kernel, dim3(1), dim3(256), 0, stream, atom_xyz, hdr);
        hipLaunchKernelGGL(count_kernel, dim3(MATOMS/256), dim3(256), 0, stream,
                           atom_xyz, hdr, starts);
        hipLaunchKernelGGL(prefix_kernel, dim3(1), dim3(1024), 0, stream, starts);
        hipLaunchKernelGGL(scatter_kernel, dim3(MATOMS/256), dim3(256), 0, stream,
                           atom_xyz, atom_batch, hdr, starts, cursors,
                           spos4, sbat, sidx);
        hipLaunchKernelGGL(prep_kernel, dim3(MATOMS/256), dim3(256), 0, stream,
                           atom_xyz, atomtypes, atom_batch,
                           Wt1, bt1, Wt2, bt2, Wt3, bt3,
                           pos4, tbuf, abat);
        hipLaunchKernelGGL(atom_main_grid, dim3(NPTS/GROUPS_PER_BLOCK), dim3(256), 0, stream,
                           xyz, batch, pos4, tbuf, abat,
                           starts, spos4, sbat, sidx, hdr,
                           Watt, We1, be1, We2, be2, We3, be3,
                           out);
    } else {
        hipLaunchKernelGGL(prep_kernel, dim3(MATOMS/256), dim3(256), 0, stream,
                           atom_xyz, atomtypes, atom_batch,
                           Wt1, bt1, Wt2, bt2, Wt3, bt3,
                           pos4, tbuf, abat);
        hipLaunchKernelGGL(atom_main_kernel, dim3(NPTS/GROUPS_PER_BLOCK), dim3(256), 0, stream,
                           xyz, batch, pos4, tbuf, abat,
                           Watt, We1, be1, We2, be2, We3, be3,
                           out);
    }
}

// Round 14
// 121.892 us; speedup vs baseline: 2.6532x; 2.6532x over previous
//
#include <hip/hip_runtime.h>
#include <cfloat>

#define NPTS   16384
#define MATOMS 8192
#define CH     16
#define ADIM   6
#define KNN    16
#define GROUPS_PER_BLOCK 8     // 32-lane groups; each group serves 2 points
#define PTSPG  2
#define BIGF   1e10f
#define SLOTS  16              // per-lane per-point capacity (lambda~2.8)
#define CHUNK  512
#define NCHUNK (MATOMS/CHUNK)  // 16
#define VMINC  4               // vmin subset = first 2048 atoms (r10-validated)
#define NPASS  (VMINC + NCHUNK) // 20

__device__ __forceinline__ float leakyf(float x) { return x >= 0.0f ? x : 0.2f * x; }

// ---------------------------------------------------------------------------
// Kernel A: per-atom feature MLP t = L3(L2(L1(atomtypes))) + packed pos4
// ---------------------------------------------------------------------------
__global__ void __launch_bounds__(256) prep_kernel(
    const float* __restrict__ atom_xyz,
    const float* __restrict__ atomtypes,
    const int*   __restrict__ atom_batch,
    const float* __restrict__ Wt1, const float* __restrict__ bt1,
    const float* __restrict__ Wt2, const float* __restrict__ bt2,
    const float* __restrict__ Wt3, const float* __restrict__ bt3,
    float4* __restrict__ pos4,
    float*  __restrict__ tbuf,
    int*    __restrict__ abatch)
{
    __shared__ float w1[CH*ADIM], w2[CH*CH], w3[CH*CH], bb1[CH], bb2[CH], bb3[CH];
    const int tid = threadIdx.x;
    if (tid < CH*ADIM) w1[tid] = Wt1[tid];
    if (tid < CH*CH)   { w2[tid] = Wt2[tid]; w3[tid] = Wt3[tid]; }
    if (tid < CH)      { bb1[tid] = bt1[tid]; bb2[tid] = bt2[tid]; bb3[tid] = bt3[tid]; }
    __syncthreads();
    const int m = blockIdx.x * 256 + tid;
    if (m >= MATOMS) return;

    float x[ADIM];
    #pragma unroll
    for (int j = 0; j < ADIM; ++j) x[j] = atomtypes[m*ADIM + j];

    float h0[CH], h1[CH], h2[CH];
    #pragma unroll
    for (int c = 0; c < CH; ++c) {
        float a = 0.0f;
        #pragma unroll
        for (int j = 0; j < ADIM; ++j) a = fmaf(w1[c*ADIM+j], x[j], a);
        h0[c] = leakyf(a + bb1[c]);
    }
    #pragma unroll
    for (int c = 0; c < CH; ++c) {
        float a = 0.0f;
        #pragma unroll
        for (int j = 0; j < CH; ++j) a = fmaf(w2[c*CH+j], h0[j], a);
        h1[c] = leakyf(a + bb2[c]);
    }
    #pragma unroll
    for (int c = 0; c < CH; ++c) {
        float a = 0.0f;
        #pragma unroll
        for (int j = 0; j < CH; ++j) a = fmaf(w3[c*CH+j], h1[j], a);
        h2[c] = leakyf(a + bb3[c]);
    }
    #pragma unroll
    for (int c = 0; c < CH; ++c) tbuf[m*CH + c] = h2[c];

    const float ax = atom_xyz[m*3+0], ay = atom_xyz[m*3+1], az = atom_xyz[m*3+2];
    // np: sum(a*a, -1) = ((ax^2 + ay^2) + az^2), no FMA contraction
    const float a2 = __fadd_rn(__fadd_rn(__fmul_rn(ax,ax), __fmul_rn(ay,ay)), __fmul_rn(az,az));
    pos4[m] = make_float4(ax, ay, az, a2);
    abatch[m] = atom_batch[m];
}

// ---------------------------------------------------------------------------
// Per-point tail: overflow guard -> (fallback full insert-scan | phase C
// exact select) -> final lexicographic pop-min merge. All bodies are the
// r10/r12-validated code, unchanged.
// ---------------------------------------------------------------------------
__device__ __forceinline__ void knn_tail(
    int c32, float px, float py, float pz, float pn2, int pb,
    int skip, int cnt, const unsigned short* seg,
    const float4* __restrict__ pos4, const int* __restrict__ abatch,
    int* idxk)
{
    int ovf = skip | (cnt > SLOTS);
    ovf |= __shfl_xor(ovf, 1);
    ovf |= __shfl_xor(ovf, 2);
    ovf |= __shfl_xor(ovf, 4);
    ovf |= __shfl_xor(ovf, 8);
    ovf |= __shfl_xor(ovf, 16);

    float bd[KNN]; int bi[KNN];
    #pragma unroll
    for (int j = 0; j < KNN; ++j) { bd[j] = FLT_MAX; bi[j] = 0x7fffffff; }

    if (ovf) {
        // validated full insert-scan fallback (rare; group-uniform)
        for (int t = 0; t < MATOMS/32; ++t) {
            const int i = t*32 + c32;
            const float4 a = pos4[i];
            const int ab = abatch[i];
            const float dot = fmaf(pz, a.z, fmaf(py, a.y, __fmul_rn(px, a.x)));
            float d2 = __fsub_rn(__fadd_rn(pn2, a.w), 2.0f * dot);
            d2 = (ab == pb) ? d2 : BIGF;
            if (d2 < bd[KNN-1]) {
                float d = d2; int id = i;
                #pragma unroll
                for (int j = 0; j < KNN; ++j) {
                    const bool sw = d < bd[j];
                    const float od = bd[j]; const int oi = bi[j];
                    bd[j] = sw ? d  : bd[j];
                    bi[j] = sw ? id : bi[j];
                    d  = sw ? od : d;
                    id = sw ? oi : id;
                }
            }
        }
    } else {
        // Phase C: EXACT d2 recompute + EXACT batch check + lexicographic
        // (d, idx) insert (order-independent-exact).
        for (int s = 0; s < cnt; ++s) {
            const int i = (int)seg[s*32];
            const float4 a = pos4[i];
            const float dot = fmaf(pz, a.z, fmaf(py, a.y, __fmul_rn(px, a.x)));
            const float d2 = __fsub_rn(__fadd_rn(pn2, a.w), 2.0f * dot);
            if (abatch[i] == pb && d2 <= bd[KNN-1]) {
                float d = d2; int id = i;
                #pragma unroll
                for (int j = 0; j < KNN; ++j) {
                    const bool sw = (d < bd[j]) || (d == bd[j] && id < bi[j]);
                    const float od = bd[j]; const int oi = bi[j];
                    bd[j] = sw ? d  : bd[j];
                    bi[j] = sw ? id : bi[j];
                    d  = sw ? od : d;
                    id = sw ? oi : id;
                }
            }
        }
    }

    // final merge: 16x pop-min over 32 lanes, lexicographic (d, idx)
    #pragma unroll
    for (int k = 0; k < KNN; ++k) {
        float d = bd[0]; int i = bi[0];
        #pragma unroll
        for (int m = 1; m <= 16; m <<= 1) {
            const float pd = __shfl_xor(d, m);
            const int   pi = __shfl_xor(i, m);
            const bool take = (pd < d) || (pd == d && pi < i);
            d = take ? pd : d;
            i = take ? pi : i;
        }
        idxk[k] = i;
        const bool win = (bd[0] == d) && (bi[0] == i);
        if (win) {
            #pragma unroll
            for (int j = 0; j < KNN-1; ++j) { bd[j] = bd[j+1]; bi[j] = bi[j+1]; }
            bd[KNN-1] = FLT_MAX; bi[KNN-1] = 0x7fffffff;
        }
    }
}

// ---------------------------------------------------------------------------
// Kernel B: 32-lane groups, 2 POINTS per group (1024 blocks).
//   Each staged atom feeds both points' lhs -> staging/barriers per point
//   halve vs r10. Unified 20-pass loop, double-buffered lpos,
//   issue-after-barrier (r10-validated schedule).
//   Passes 0..3: dual per-lane lhs-min over first-2048 subset (lazy batch).
//   Pass 4: per-point tau via 16 pop-mins over 32 lane minima (validated).
//   Passes 4..19: dual lean filter, per-point per-lane LDS segments.
//   Tails: knn_tail per point (validated). Epilogue packed: lanes 0-15 ->
//   point0, lanes 16-31 -> point1 (width-16 shuffles confine each half).
// ---------------------------------------------------------------------------
__global__ void __launch_bounds__(256) atom_main_kernel(
    const float* __restrict__ xyz,
    const int*   __restrict__ batch,
    const float4* __restrict__ pos4,
    const float* __restrict__ tbuf,
    const int*   __restrict__ abatch,
    const float* __restrict__ Watt,
    const float* __restrict__ We1, const float* __restrict__ be1,
    const float* __restrict__ We2, const float* __restrict__ be2,
    const float* __restrict__ We3, const float* __restrict__ be3,
    float* __restrict__ out)
{
    __shared__ float lw1t[CH*CH], lw2t[CH*CH], lw3t[CH*CH];
    __shared__ float lb1[CH], lb2[CH], lb3[CH], lwatt[KNN];
    __shared__ unsigned short lbuf[GROUPS_PER_BLOCK * PTSPG * SLOTS * 32];
    __shared__ float4 lpos[2][CHUNK];
    const int tid = threadIdx.x;
    lw1t[tid] = We1[(tid & 15)*CH + (tid >> 4)];
    lw2t[tid] = We2[(tid & 15)*CH + (tid >> 4)];
    lw3t[tid] = We3[(tid & 15)*CH + (tid >> 4)];
    if (tid < CH) { lb1[tid] = be1[tid]; lb2[tid] = be2[tid]; lb3[tid] = be3[tid]; lwatt[tid] = Watt[tid]; }

    const int c32 = tid & 31;
    const int grp = tid >> 5;
    const int n0  = (blockIdx.x * GROUPS_PER_BLOCK + grp) * PTSPG;
    const int n1  = n0 + 1;

    const float px0 = xyz[n0*3+0], py0 = xyz[n0*3+1], pz0 = xyz[n0*3+2];
    const float px1 = xyz[n1*3+0], py1 = xyz[n1*3+1], pz1 = xyz[n1*3+2];
    // np: sum(x*x, -1) sequential, no FMA
    const float pn20 = __fadd_rn(__fadd_rn(__fmul_rn(px0,px0), __fmul_rn(py0,py0)), __fmul_rn(pz0,pz0));
    const float pn21 = __fadd_rn(__fadd_rn(__fmul_rn(px1,px1), __fmul_rn(py1,py1)), __fmul_rn(pz1,pz1));
    const int pb0 = batch[n0];
    const int pb1 = batch[n1];

    // prologue: stage chunk 0 into buffer 0
    {
        const float4 q0 = pos4[tid];
        const float4 q1 = pos4[tid+256];
        lpos[0][tid] = q0; lpos[0][tid+256] = q1;
    }

    float vmin0 = FLT_MAX, vmin1 = FLT_MAX;
    float tauf0 = 0.0f, tauf1 = 0.0f;
    int   skip0 = 0, skip1 = 0;
    int   cnt0 = 0, cnt1 = 0;
    unsigned short* seg0 = &lbuf[(grp*PTSPG + 0) * (SLOTS*32) + c32];
    unsigned short* seg1 = &lbuf[(grp*PTSPG + 1) * (SLOTS*32) + c32];

    for (int g = 0; g < NPASS; ++g) {
        const int cur = g & 1;
        __syncthreads();                     // buf[cur] ready; buf[cur^1] free
        // issue next-chunk loads AFTER the barrier (not drained by it)
        float4 q0, q1;
        const bool pf = (g+1 < NPASS);
        if (pf) {
            const int nc = (g+1 < VMINC) ? (g+1) : (g+1-VMINC);
            const int base = nc*CHUNK;
            q0 = pos4[base+tid]; q1 = pos4[base+tid+256];
        }
        if (g == VMINC) {
            // per-point tau: 16 d-only pop-mins over 32 lane minima.
            // Validity: each pop removes >=1 lane = >=1 distinct in-batch
            // atom with lhs <= tau  =>  tau >= lhs of the 16th-nearest.
            float tau0 = FLT_MAX, tau1 = FLT_MAX;
            {
                float v = vmin0;
                #pragma unroll
                for (int k = 0; k < KNN; ++k) {
                    float d = v;
                    d = fminf(d, __shfl_xor(d, 1));
                    d = fminf(d, __shfl_xor(d, 2));
                    d = fminf(d, __shfl_xor(d, 4));
                    d = fminf(d, __shfl_xor(d, 8));
                    d = fminf(d, __shfl_xor(d, 16));
                    tau0 = d;
                    if (v == d) v = FLT_MAX; // remove popped (ties safe)
                }
            }
            {
                float v = vmin1;
                #pragma unroll
                for (int k = 0; k < KNN; ++k) {
                    float d = v;
                    d = fminf(d, __shfl_xor(d, 1));
                    d = fminf(d, __shfl_xor(d, 2));
                    d = fminf(d, __shfl_xor(d, 4));
                    d = fminf(d, __shfl_xor(d, 8));
                    d = fminf(d, __shfl_xor(d, 16));
                    tau1 = d;
                    if (v == d) v = FLT_MAX;
                }
            }
            skip0 = !(tau0 < BIGF);          // group-uniform
            skip1 = !(tau1 < BIGF);
            tauf0 = skip0 ? -FLT_MAX : tau0 + (1e-5f*(fabsf(pn20) + fabsf(tau0)) + 1e-2f);
            tauf1 = skip1 ? -FLT_MAX : tau1 + (1e-5f*(fabsf(pn21) + fabsf(tau1)) + 1e-2f);
        }
        if (g < VMINC) {
            // dual vmin scan (subset chunks 0..3); lazy global batch check
            #pragma unroll 4
            for (int t = 0; t < CHUNK/32; ++t) {
                const int il = t*32 + c32;
                const float4 a = lpos[cur][il];
                const float dot0 = fmaf(pz0, a.z, fmaf(py0, a.y, __fmul_rn(px0, a.x)));
                const float lhs0 = fmaf(-2.0f, dot0, a.w);
                const float dot1 = fmaf(pz1, a.z, fmaf(py1, a.y, __fmul_rn(px1, a.x)));
                const float lhs1 = fmaf(-2.0f, dot1, a.w);
                if (lhs0 < vmin0) { if (abatch[g*CHUNK + il] == pb0) vmin0 = lhs0; }
                if (lhs1 < vmin1) { if (abatch[g*CHUNK + il] == pb1) vmin1 = lhs1; }
            }
        } else {
            // dual lean distance-only filter scan
            const int cb = g - VMINC;
            #pragma unroll 4
            for (int t = 0; t < CHUNK/32; ++t) {
                const int il = t*32 + c32;
                const float4 a = lpos[cur][il];
                const float dot0 = fmaf(pz0, a.z, fmaf(py0, a.y, __fmul_rn(px0, a.x)));
                const float lhs0 = fmaf(-2.0f, dot0, a.w);
                const float dot1 = fmaf(pz1, a.z, fmaf(py1, a.y, __fmul_rn(px1, a.x)));
                const float lhs1 = fmaf(-2.0f, dot1, a.w);
                const int gi = cb*CHUNK + il;
                if (lhs0 <= tauf0) {
                    if (cnt0 < SLOTS) seg0[cnt0*32] = (unsigned short)gi;
                    ++cnt0;
                }
                if (lhs1 <= tauf1) {
                    if (cnt1 < SLOTS) seg1[cnt1*32] = (unsigned short)gi;
                    ++cnt1;
                }
            }
        }
        if (pf) {                            // write-late: loads landed by now
            lpos[cur^1][tid] = q0; lpos[cur^1][tid+256] = q1;
        }
    }

    // ---- tails (validated): exact selection per point
    int idxk0[KNN], idxk1[KNN];
    knn_tail(c32, px0, py0, pz0, pn20, pb0, skip0, cnt0, seg0, pos4, abatch, idxk0);
    knn_tail(c32, px1, py1, pz1, pn21, pb1, skip1, cnt1, seg1, pos4, abatch, idxk1);

    // ---- packed epilogue: lanes 0-15 -> point0, lanes 16-31 -> point1.
    // Width-16 shuffles confine each half; numerics identical to validated.
    {
        const int half = (tid >> 4) & 1;
        const int c = tid & 15;
        const int myn = half ? n1 : n0;
        const float px = half ? px1 : px0;
        const float py = half ? py1 : py0;
        const float pz = half ? pz1 : pz0;
        int myidx[KNN];
        #pragma unroll
        for (int k = 0; k < KNN; ++k) myidx[k] = half ? idxk1[k] : idxk0[k];

        float ac0 = 0.0f, ac1 = 0.0f, ac2 = 0.0f;
        #pragma unroll
        for (int k = 0; k < KNN; ++k) {
            const int j = myidx[k];
            const float4 a = pos4[j];
            const float v0 = __fsub_rn(px, a.x);
            const float v1 = __fsub_rn(py, a.y);
            const float v2 = __fsub_rn(pz, a.z);
            // np: dists = sum(vecs*vecs, -1), sequential, no FMA (recomputed)
            const float dist = __fadd_rn(__fadd_rn(__fmul_rn(v0,v0), __fmul_rn(v1,v1)), __fmul_rn(v2,v2));
            const float w = 1.0f / __fadd_rn(dist, 1e-8f);   // power(x, -1.0)
            const float nv0 = __fmul_rn(v0, w);
            const float nv1 = __fmul_rn(v1, w);
            const float nv2 = __fmul_rn(v2, w);
            const float fc = tbuf[(size_t)j * CH + c];
            const float fw = __fmul_rn(fc, lwatt[k]);
            ac0 = fmaf(nv0, fw, ac0);
            ac1 = fmaf(nv1, fw, ac1);
            ac2 = fmaf(nv2, fw, ac2);
        }
        const float s = __fadd_rn(__fadd_rn(__fmul_rn(ac0,ac0), __fmul_rn(ac1,ac1)),
                                  __fmul_rn(ac2,ac2));
        const float fx = sqrtf(s);

        float a1 = 0.0f;
        #pragma unroll
        for (int j = 0; j < CH; ++j) {
            const float fj = __shfl(fx, j, 16);
            a1 = fmaf(lw1t[j*CH + c], fj, a1);
        }
        const float g1 = leakyf(a1 + lb1[c]);

        float a2 = 0.0f;
        #pragma unroll
        for (int j = 0; j < CH; ++j) {
            const float gj = __shfl(g1, j, 16);
            a2 = fmaf(lw2t[j*CH + c], gj, a2);
        }
        const float g2 = leakyf(a2 + lb2[c]);

        float a3 = 0.0f;
        #pragma unroll
        for (int j = 0; j < CH; ++j) {
            const float gj = __shfl(g2, j, 16);
            a3 = fmaf(lw3t[j*CH + c], gj, a3);
        }
        out[(size_t)myn*CH + c] = a3 + lb3[c];
    }
}

// ---------------------------------------------------------------------------
extern "C" void kernel_launch(void* const* d_in, const int* in_sizes, int n_in,
                              void* d_out, int out_size, void* d_ws, size_t ws_size,
                              hipStream_t stream)
{
    (void)in_sizes; (void)n_in; (void)out_size; (void)ws_size;
    const float* xyz        = (const float*)d_in[0];
    const float* atom_xyz   = (const float*)d_in[1];
    const float* atomtypes  = (const float*)d_in[2];
    const int*   batch      = (const int*)d_in[3];
    const int*   atom_batch = (const int*)d_in[4];
    const float* Wt1 = (const float*)d_in[5];
    const float* bt1 = (const float*)d_in[6];
    const float* Wt2 = (const float*)d_in[7];
    const float* bt2 = (const float*)d_in[8];
    const float* Wt3 = (const float*)d_in[9];
    const float* bt3 = (const float*)d_in[10];
    const float* Watt = (const float*)d_in[11];
    const float* We1 = (const float*)d_in[12];
    const float* be1 = (const float*)d_in[13];
    const float* We2 = (const float*)d_in[14];
    const float* be2 = (const float*)d_in[15];
    const float* We3 = (const float*)d_in[16];
    const float* be3 = (const float*)d_in[17];

    char* ws = (char*)d_ws;
    float4* pos4  = (float4*)ws;                          // 8192*16  = 131072 B
    float*  tbuf  = (float*)(ws + 131072);                // 8192*64  = 524288 B
    int*    abat  = (int*)(ws + 131072 + 524288);         // 8192*4   =  32768 B
    float*  out   = (float*)d_out;

    hipLaunchKernelGGL(prep_kernel, dim3(MATOMS/256), dim3(256), 0, stream,
                       atom_xyz, atomtypes, atom_batch,
                       Wt1, bt1, Wt2, bt2, Wt3, bt3,
                       pos4, tbuf, abat);
    hipLaunchKernelGGL(atom_main_kernel, dim3(NPTS/(GROUPS_PER_BLOCK*PTSPG)), dim3(256), 0, stream,
                       xyz, batch, pos4, tbuf, abat,
                       Watt, We1, be1, We2, be2, We3, be3,
                       out);
}